// Round 8
// baseline (143.702 us; speedup 1.0000x reference)
//
#include <hip/hip_runtime.h>
#include <hip/hip_bf16.h>

#define N 1024
#define D 64
#define H1 128
#define H2 64
#define FLAG_THRESH 0.015f
#define H1PAD 136   // f16 LDS row stride: 272 B = 17*16B (aligned b128, 2-way banks only)

typedef _Float16 half8 __attribute__((ext_vector_type(8)));
typedef float float4v __attribute__((ext_vector_type(4)));

// ---------------------------------------------------------------------------
// K1: pre-activations, exact f64 + f16 copies.
//   A = X @ W1[:64,:] + b1   (1024 x 128)
//   B = X @ W1[64:,:]        (1024 x 128)
// ---------------------------------------------------------------------------
__global__ __launch_bounds__(128) void precompute_kernel(
    const float* __restrict__ X, const float* __restrict__ W1,
    const float* __restrict__ b1,
    double* __restrict__ A64, double* __restrict__ B64,
    _Float16* __restrict__ A16, _Float16* __restrict__ B16)
{
    int i = blockIdx.x;
    int k = threadIdx.x;
    double a = (double)b1[k];
    double b = 0.0;
    for (int c = 0; c < D; ++c) {
        double x = (double)X[i * D + c];              // wave-uniform
        a += x * (double)W1[c * H1 + k];
        b += x * (double)W1[(D + c) * H1 + k];
    }
    A64[i * H1 + k] = a;
    B64[i * H1 + k] = b;
    A16[i * H1 + k] = (_Float16)(float)a;
    B16[i * H1 + k] = (_Float16)(float)b;
}

// ---------------------------------------------------------------------------
// K2: MFMA pair-MLP. Block = 16 i-rows x 64 j-cols = 1024 pairs.
// OPERAND-SWAPPED GEMM: A = W2 (rows = o), B = h = relu(A16[i]+B16[j])
// (cols = pairs). D[row=o_local][col=pair]: each lane (pair = lane&15) holds
// S for o = quad*4+reg+16*nt -> layer-3 reduce is IN-LANE + 2 shfl_xor.
// ---------------------------------------------------------------------------
__global__ __launch_bounds__(256, 3) void pair_mlp_kernel(
    const _Float16* __restrict__ A16, const _Float16* __restrict__ B16,
    const float* __restrict__ W2, const float* __restrict__ b2,
    const float* __restrict__ W3, float* __restrict__ dmat)
{
    __shared__ _Float16 As16[16 * H1PAD];
    __shared__ _Float16 Bs16[64 * H1PAD];
    __shared__ _Float16 W2t[64 * H1PAD];   // transposed: W2t[n][k]

    int tid = threadIdx.x;
    int it = blockIdx.x >> 4;      // 0..63
    int jt = blockIdx.x & 15;      // 0..15
    int ti = it << 4;              // i0
    int tj = jt << 6;              // j0

    // ---- stage A16 rows (16x128 f16): 8 f16 per thread
    {
        int row = tid >> 4;
        int col = (tid & 15) << 3;
        *(half8*)&As16[row * H1PAD + col] =
            *(const half8*)&A16[(size_t)(ti + row) * H1 + col];
    }
    // ---- stage B16 rows (64x128 f16): 32 f16 per thread
    #pragma unroll
    for (int r = 0; r < 4; ++r) {
        int v = tid + r * 256;
        int row = v >> 4;
        int col = (v & 15) << 3;
        *(half8*)&Bs16[row * H1PAD + col] =
            *(const half8*)&B16[(size_t)(tj + row) * H1 + col];
    }
    // ---- stage W2 transposed to f16: W2t[n][k] = W2[k][n]
    #pragma unroll
    for (int r = 0; r < 32; ++r) {
        int idx = tid + r * 256;   // 0..8191
        int k = idx >> 6;
        int n = idx & 63;
        W2t[n * H1PAD + k] = (_Float16)W2[idx];
    }
    __syncthreads();

    int lane = tid & 63;
    int wave = tid >> 6;
    int quad = lane >> 4;          // 0..3
    int m = lane & 15;             // A-frag row (o_local) AND B-frag col (pair)

    // ---- A-frags: W2 fully in registers. afrag[ks][nt]: A[m][k] = W2[k][m+16nt]
    half8 afrag[4][4];
    #pragma unroll
    for (int ks = 0; ks < 4; ++ks)
        #pragma unroll
        for (int nt = 0; nt < 4; ++nt)
            afrag[ks][nt] = *(const half8*)&W2t[(m + 16 * nt) * H1PAD + quad * 8 + 32 * ks];

    // ---- per-lane epilogue constants: this lane's o for (nt,reg) = quad*4+reg+16*nt
    float b2x[4][4], w3x[4][4];
    #pragma unroll
    for (int nt = 0; nt < 4; ++nt)
        #pragma unroll
        for (int reg = 0; reg < 4; ++reg) {
            int o = (quad << 2) + reg + (nt << 4);
            b2x[nt][reg] = b2[o];
            w3x[nt][reg] = W3[o * 2 + 1] - W3[o * 2 + 0];
        }

    const half8 zero8 = {0, 0, 0, 0, 0, 0, 0, 0};

    #pragma unroll 1
    for (int jq = 0; jq < 4; ++jq) {
        int jj0 = jq << 4;
        half8 hb[4];               // this lane's pair j = tj + jj0 + m
        #pragma unroll
        for (int ks = 0; ks < 4; ++ks)
            hb[ks] = *(const half8*)&Bs16[(jj0 + m) * H1PAD + quad * 8 + 32 * ks];

        #pragma unroll 1
        for (int i4 = 0; i4 < 4; ++i4) {
            int ii = (wave << 2) + i4;

            float4v acc[4];
            #pragma unroll
            for (int nt = 0; nt < 4; ++nt)
                acc[nt] = (float4v){b2x[nt][0], b2x[nt][1], b2x[nt][2], b2x[nt][3]};

            #pragma unroll
            for (int ks = 0; ks < 4; ++ks) {
                half8 ha = *(const half8*)&As16[ii * H1PAD + quad * 8 + 32 * ks]; // broadcast
                half8 h = __builtin_elementwise_max(ha + hb[ks], zero8);          // relu
                #pragma unroll
                for (int nt = 0; nt < 4; ++nt)
                    acc[nt] = __builtin_amdgcn_mfma_f32_16x16x32_f16(afrag[ks][nt], h, acc[nt], 0, 0, 0);
            }

            // ---- fused layer 3: in-lane over 16 o's, then quad-sum via shfl_xor
            float s = 0.f;
            #pragma unroll
            for (int nt = 0; nt < 4; ++nt)
                #pragma unroll
                for (int reg = 0; reg < 4; ++reg)
                    s = fmaf(fmaxf(acc[nt][reg], 0.f), w3x[nt][reg], s);
            s += __shfl_xor(s, 16, 64);
            s += __shfl_xor(s, 32, 64);
            if (quad == 0) {
                // 16 lanes store 16 consecutive floats (coalesced 64 B)
                dmat[(size_t)(ti + ii) * N + (tj + jj0 + m)] = s;
            }
        }
    }
}

// ---------------------------------------------------------------------------
// K3: fused epilogue + f64 repair.
// Main phase: D = 0.5*(d[i][j]+d[j][i]) + b3d + (g1-g0) with fast __logf;
//             out = D > 0; flag |D| < thresh into LDS.
// Repair phase: PER-WAVE, barrier-free. h1s[wave] is wave-private; DS ops
// are in-order per wave, so an s_waitcnt lgkmcnt(0) suffices between the
// cross-lane LDS writes and reads. Waves without flags exit immediately.
// ---------------------------------------------------------------------------
__global__ __launch_bounds__(256) void epilogue_repair_kernel(
    const float* __restrict__ dmat, const double* __restrict__ A64,
    const double* __restrict__ B64, const float* __restrict__ W2,
    const float* __restrict__ b2, const float* __restrict__ W3,
    const float* __restrict__ b3, const float* __restrict__ u,
    float* __restrict__ out)
{
    __shared__ float T1[32][33];
    __shared__ float T2[32][33];
    __shared__ unsigned int lflags[1024];   // cap = pairs/block: cannot overflow
    __shared__ unsigned int lcnt;
    __shared__ double h1s[4][2][H1];        // 8 KB, wave-private slices

    int bi = blockIdx.x >> 5;
    int bj = blockIdx.x & 31;
    int i0 = bi * 32, j0 = bj * 32;
    int tid = threadIdx.x;
    int r = tid >> 3;
    int c4 = (tid & 7) << 2;
    if (tid == 0) lcnt = 0;

    int a = tid >> 3;
    int b0 = (tid & 7) << 2;
    int ij0 = (i0 + a) * N + (j0 + b0);

    // hoisted: overlap u HBM latency with tile staging
    float4 u01 = *(const float4*)&u[((size_t)ij0) * 2];       // pairs q=0,1
    float4 u23 = *(const float4*)&u[((size_t)ij0) * 2 + 4];   // pairs q=2,3

    *(float4*)&T1[r][c4] = *(const float4*)&dmat[(size_t)(i0 + r) * N + j0 + c4];
    *(float4*)&T2[r][c4] = *(const float4*)&dmat[(size_t)(j0 + r) * N + i0 + c4];
    __syncthreads();

    float b3d = b3[1] - b3[0];
    float uu[8] = {u01.x, u01.y, u01.z, u01.w, u23.x, u23.y, u23.z, u23.w};

    float4 res;
    float* resp = &res.x;
    #pragma unroll
    for (int q = 0; q < 4; ++q) {
        int b = b0 + q;
        // fast-log gumbel: |err| ~1e-5 << FLAG_THRESH margin; flagged pairs
        // are re-resolved exactly below.
        float g0 = -__logf(-__logf(uu[2 * q] + 1e-10f) + 1e-10f);
        float g1 = -__logf(-__logf(uu[2 * q + 1] + 1e-10f) + 1e-10f);
        float Dv = 0.5f * (T1[a][b] + T2[b][a]) + b3d + (g1 - g0);
        resp[q] = Dv > 0.f ? 1.f : 0.f;
        if (fabsf(Dv) < FLAG_THRESH) {
            unsigned int idx = atomicAdd(&lcnt, 1u);   // LDS atomic
            lflags[idx] = (unsigned int)(ij0 + q);
        }
    }
    *(float4*)&out[ij0] = res;

    // publishes lflags/lcnt AND drains main-phase out-stores (vmcnt(0) before
    // s_barrier) so repair overwrites land after.
    __syncthreads();

    // ---------------- repair phase (exact f64, per-wave) ----------------
    unsigned int nl = lcnt;
    int lane = tid & 63;
    int wave = tid >> 6;
    double w3dd = (double)W3[lane * 2 + 1] - (double)W3[lane * 2 + 0];
    double b2d = (double)b2[lane];

    for (unsigned int f = wave; f < nl; f += 4) {
        int ij = (int)lflags[f];
        int i = ij >> 10, j = ij & (N - 1);
        {   // lane = k (two k's per lane), coalesced f64 loads
            int k0 = lane, k1 = lane + 64;
            double ai0 = A64[(size_t)i * H1 + k0], ai1 = A64[(size_t)i * H1 + k1];
            double aj0 = A64[(size_t)j * H1 + k0], aj1 = A64[(size_t)j * H1 + k1];
            double bi0 = B64[(size_t)i * H1 + k0], bi1 = B64[(size_t)i * H1 + k1];
            double bj0 = B64[(size_t)j * H1 + k0], bj1 = B64[(size_t)j * H1 + k1];
            double v;
            v = ai0 + bj0; h1s[wave][0][k0] = v > 0.0 ? v : 0.0;
            v = ai1 + bj1; h1s[wave][0][k1] = v > 0.0 ? v : 0.0;
            v = aj0 + bi0; h1s[wave][1][k0] = v > 0.0 ? v : 0.0;
            v = aj1 + bi1; h1s[wave][1][k1] = v > 0.0 ? v : 0.0;
        }
        // wave-local LDS fence: writes above complete before reads below
        asm volatile("s_waitcnt lgkmcnt(0)" ::: "memory");
        __builtin_amdgcn_wave_barrier();
        double sa = b2d, sb = b2d;
        #pragma unroll 4
        for (int k = 0; k < H1; ++k) {
            double w = (double)W2[k * H2 + lane];   // coalesced, L1-resident
            sa += h1s[wave][0][k] * w;
            sb += h1s[wave][1][k] * w;
        }
        if (sa < 0.0) sa = 0.0;
        if (sb < 0.0) sb = 0.0;
        double da = sa * w3dd;
        double db = sb * w3dd;
        #pragma unroll
        for (int off = 32; off > 0; off >>= 1) {
            da += __shfl_down(da, off, 64);
            db += __shfl_down(db, off, 64);
        }
        if (lane == 0) {
            double b3dd = (double)b3[1] - (double)b3[0];
            double u0 = (double)u[(((size_t)ij) << 1) + 0];
            double u1 = (double)u[(((size_t)ij) << 1) + 1];
            double g0 = -log(-log(u0 + 1e-10) + 1e-10);
            double g1 = -log(-log(u1 + 1e-10) + 1e-10);
            double Dv = 0.5 * (da + db) + b3dd + (g1 - g0);
            out[ij] = Dv > 0.0 ? 1.f : 0.f;
        }
        // DS in-order per wave: next iter's writes can't pass this iter's
        // reads; wave_barrier keeps the compiler from trying.
        __builtin_amdgcn_wave_barrier();
    }
}

// ---------------------------------------------------------------------------
extern "C" void kernel_launch(void* const* d_in, const int* in_sizes, int n_in,
                              void* d_out, int out_size, void* d_ws, size_t ws_size,
                              hipStream_t stream) {
    const float* X  = (const float*)d_in[0];
    const float* W1 = (const float*)d_in[1];
    const float* b1 = (const float*)d_in[2];
    const float* W2 = (const float*)d_in[3];
    const float* b2 = (const float*)d_in[4];
    const float* W3 = (const float*)d_in[5];
    const float* b3 = (const float*)d_in[6];
    const float* u  = (const float*)d_in[7];
    float* out = (float*)d_out;

    // workspace layout (doubles first for alignment)
    double* A64 = (double*)d_ws;                         // 1 MB
    double* B64 = A64 + (size_t)N * H1;                  // 1 MB
    float* dmat = (float*)(B64 + (size_t)N * H1);        // 4 MB
    _Float16* A16 = (_Float16*)(dmat + (size_t)N * N);   // 256 KB
    _Float16* B16 = A16 + (size_t)N * H1;                // 256 KB

    precompute_kernel<<<N, 128, 0, stream>>>(X, W1, b1, A64, B64, A16, B16);
    pair_mlp_kernel<<<(N / 16) * (N / 64), 256, 0, stream>>>(A16, B16, W2, b2, W3, dmat);
    epilogue_repair_kernel<<<(N / 32) * (N / 32), 256, 0, stream>>>(
        dmat, A64, B64, W2, b2, W3, b3, u, out);
}

// Round 9
// 131.154 us; speedup vs baseline: 1.0957x; 1.0957x over previous
//
#include <hip/hip_runtime.h>
#include <hip/hip_bf16.h>

#define N 1024
#define D 64
#define H1 128
#define H2 64
#define FLAG_THRESH 0.015f
#define H1PAD 136   // f16 LDS row stride: 272 B = 17*16B (aligned b128, 2-way banks only)

typedef _Float16 half8 __attribute__((ext_vector_type(8)));
typedef float float4v __attribute__((ext_vector_type(4)));

// ---------------------------------------------------------------------------
// K1: pre-activations, exact f64 + f16 copies.
//   A = X @ W1[:64,:] + b1   (1024 x 128)
//   B = X @ W1[64:,:]        (1024 x 128)
// ---------------------------------------------------------------------------
__global__ __launch_bounds__(128) void precompute_kernel(
    const float* __restrict__ X, const float* __restrict__ W1,
    const float* __restrict__ b1,
    double* __restrict__ A64, double* __restrict__ B64,
    _Float16* __restrict__ A16, _Float16* __restrict__ B16)
{
    int i = blockIdx.x;
    int k = threadIdx.x;
    double a = (double)b1[k];
    double b = 0.0;
    for (int c = 0; c < D; ++c) {
        double x = (double)X[i * D + c];              // wave-uniform
        a += x * (double)W1[c * H1 + k];
        b += x * (double)W1[(D + c) * H1 + k];
    }
    A64[i * H1 + k] = a;
    B64[i * H1 + k] = b;
    A16[i * H1 + k] = (_Float16)(float)a;
    B16[i * H1 + k] = (_Float16)(float)b;
}

// ---------------------------------------------------------------------------
// K2: MFMA pair-MLP. Block = 16 i-rows x 64 j-cols = 1024 pairs.
// OPERAND-SWAPPED GEMM: A = W2 (rows = o), B = h = relu(A16[i]+B16[j])
// (cols = pairs). D[row=o_local][col=pair]: each lane (pair = lane&15) holds
// S for o = quad*4+reg+16*nt -> layer-3 reduce is IN-LANE + 2 shfl_xor.
// ---------------------------------------------------------------------------
__global__ __launch_bounds__(256, 3) void pair_mlp_kernel(
    const _Float16* __restrict__ A16, const _Float16* __restrict__ B16,
    const float* __restrict__ W2, const float* __restrict__ b2,
    const float* __restrict__ W3, float* __restrict__ dmat)
{
    __shared__ _Float16 As16[16 * H1PAD];
    __shared__ _Float16 Bs16[64 * H1PAD];
    __shared__ _Float16 W2t[64 * H1PAD];   // transposed: W2t[n][k]

    int tid = threadIdx.x;
    int it = blockIdx.x >> 4;      // 0..63
    int jt = blockIdx.x & 15;      // 0..15
    int ti = it << 4;              // i0
    int tj = jt << 6;              // j0

    // ---- stage A16 rows (16x128 f16): 8 f16 per thread
    {
        int row = tid >> 4;
        int col = (tid & 15) << 3;
        *(half8*)&As16[row * H1PAD + col] =
            *(const half8*)&A16[(size_t)(ti + row) * H1 + col];
    }
    // ---- stage B16 rows (64x128 f16): 32 f16 per thread
    #pragma unroll
    for (int r = 0; r < 4; ++r) {
        int v = tid + r * 256;
        int row = v >> 4;
        int col = (v & 15) << 3;
        *(half8*)&Bs16[row * H1PAD + col] =
            *(const half8*)&B16[(size_t)(tj + row) * H1 + col];
    }
    // ---- stage W2 transposed to f16: W2t[n][k] = W2[k][n]
    #pragma unroll
    for (int r = 0; r < 32; ++r) {
        int idx = tid + r * 256;   // 0..8191
        int k = idx >> 6;
        int n = idx & 63;
        W2t[n * H1PAD + k] = (_Float16)W2[idx];
    }
    __syncthreads();

    int lane = tid & 63;
    int wave = tid >> 6;
    int quad = lane >> 4;          // 0..3
    int m = lane & 15;             // A-frag row (o_local) AND B-frag col (pair)

    // ---- A-frags: W2 fully in registers. afrag[ks][nt]: A[m][k] = W2[k][m+16nt]
    half8 afrag[4][4];
    #pragma unroll
    for (int ks = 0; ks < 4; ++ks)
        #pragma unroll
        for (int nt = 0; nt < 4; ++nt)
            afrag[ks][nt] = *(const half8*)&W2t[(m + 16 * nt) * H1PAD + quad * 8 + 32 * ks];

    // ---- per-lane epilogue constants: this lane's o for (nt,reg) = quad*4+reg+16*nt
    float b2x[4][4], w3x[4][4];
    #pragma unroll
    for (int nt = 0; nt < 4; ++nt)
        #pragma unroll
        for (int reg = 0; reg < 4; ++reg) {
            int o = (quad << 2) + reg + (nt << 4);
            b2x[nt][reg] = b2[o];
            w3x[nt][reg] = W3[o * 2 + 1] - W3[o * 2 + 0];
        }

    const half8 zero8 = {0, 0, 0, 0, 0, 0, 0, 0};

    #pragma unroll 1
    for (int jq = 0; jq < 4; ++jq) {
        int jj0 = jq << 4;
        half8 hb[4];               // this lane's pair j = tj + jj0 + m
        #pragma unroll
        for (int ks = 0; ks < 4; ++ks)
            hb[ks] = *(const half8*)&Bs16[(jj0 + m) * H1PAD + quad * 8 + 32 * ks];

        #pragma unroll 1
        for (int i4 = 0; i4 < 4; ++i4) {
            int ii = (wave << 2) + i4;

            float4v acc[4];
            #pragma unroll
            for (int nt = 0; nt < 4; ++nt)
                acc[nt] = (float4v){b2x[nt][0], b2x[nt][1], b2x[nt][2], b2x[nt][3]};

            #pragma unroll
            for (int ks = 0; ks < 4; ++ks) {
                half8 ha = *(const half8*)&As16[ii * H1PAD + quad * 8 + 32 * ks]; // broadcast
                half8 h = __builtin_elementwise_max(ha + hb[ks], zero8);          // relu
                #pragma unroll
                for (int nt = 0; nt < 4; ++nt)
                    acc[nt] = __builtin_amdgcn_mfma_f32_16x16x32_f16(afrag[ks][nt], h, acc[nt], 0, 0, 0);
            }

            // ---- fused layer 3: in-lane over 16 o's, then quad-sum via shfl_xor
            float s = 0.f;
            #pragma unroll
            for (int nt = 0; nt < 4; ++nt)
                #pragma unroll
                for (int reg = 0; reg < 4; ++reg)
                    s = fmaf(fmaxf(acc[nt][reg], 0.f), w3x[nt][reg], s);
            s += __shfl_xor(s, 16, 64);
            s += __shfl_xor(s, 32, 64);
            if (quad == 0) {
                // 16 lanes store 16 consecutive floats (coalesced 64 B)
                dmat[(size_t)(ti + ii) * N + (tj + jj0 + m)] = s;
            }
        }
    }
}

// ---------------------------------------------------------------------------
// K3: fused epilogue + f64 repair.
// Main phase: D = 0.5*(d[i][j]+d[j][i]) + b3d + log(l0/l1) with fast __logf;
//             out = D > 0; flag |D| < thresh into LDS.
// Repair phase: per-wave; 8 independent f64 accumulator chains (latency),
// gumbel logs on lanes 0,1 in parallel; u prefetched at pair top.
// ---------------------------------------------------------------------------
__global__ __launch_bounds__(256) void epilogue_repair_kernel(
    const float* __restrict__ dmat, const double* __restrict__ A64,
    const double* __restrict__ B64, const float* __restrict__ W2,
    const float* __restrict__ b2, const float* __restrict__ W3,
    const float* __restrict__ b3, const float* __restrict__ u,
    float* __restrict__ out)
{
    __shared__ float T1[32][33];
    __shared__ float T2[32][33];
    __shared__ unsigned int lflags[1024];   // cap = pairs/block: cannot overflow
    __shared__ unsigned int lcnt;
    __shared__ double h1s[4][2][H1];        // 8 KB, wave-private slices

    int bi = blockIdx.x >> 5;
    int bj = blockIdx.x & 31;
    int i0 = bi * 32, j0 = bj * 32;
    int tid = threadIdx.x;
    int r = tid >> 3;
    int c4 = (tid & 7) << 2;
    if (tid == 0) lcnt = 0;

    int a = tid >> 3;
    int b0 = (tid & 7) << 2;
    int ij0 = (i0 + a) * N + (j0 + b0);

    // hoisted: overlap u HBM latency with tile staging
    float4 u01 = *(const float4*)&u[((size_t)ij0) * 2];       // pairs q=0,1
    float4 u23 = *(const float4*)&u[((size_t)ij0) * 2 + 4];   // pairs q=2,3

    *(float4*)&T1[r][c4] = *(const float4*)&dmat[(size_t)(i0 + r) * N + j0 + c4];
    *(float4*)&T2[r][c4] = *(const float4*)&dmat[(size_t)(j0 + r) * N + i0 + c4];
    __syncthreads();

    float b3d = b3[1] - b3[0];
    float uu[8] = {u01.x, u01.y, u01.z, u01.w, u23.x, u23.y, u23.z, u23.w};

    float4 res;
    float* resp = &res.x;
    #pragma unroll
    for (int q = 0; q < 4; ++q) {
        int b = b0 + q;
        // g1 - g0 = log(l0/l1), l = -log(u+eps)+eps. Fast-log err ~1e-5 <<
        // FLAG_THRESH margin; flagged pairs re-resolved exactly below.
        float l0 = -__logf(uu[2 * q] + 1e-10f) + 1e-10f;
        float l1 = -__logf(uu[2 * q + 1] + 1e-10f) + 1e-10f;
        float Dv = 0.5f * (T1[a][b] + T2[b][a]) + b3d + __logf(l0 / l1);
        resp[q] = Dv > 0.f ? 1.f : 0.f;
        if (fabsf(Dv) < FLAG_THRESH) {
            unsigned int idx = atomicAdd(&lcnt, 1u);   // LDS atomic
            lflags[idx] = (unsigned int)(ij0 + q);
        }
    }
    *(float4*)&out[ij0] = res;

    // publishes lflags/lcnt AND drains main-phase out-stores so repair
    // overwrites land after.
    __syncthreads();

    // ---------------- repair phase (exact f64, per-wave) ----------------
    unsigned int nl = lcnt;
    int lane = tid & 63;
    int wave = tid >> 6;
    double w3dd = (double)W3[lane * 2 + 1] - (double)W3[lane * 2 + 0];
    double b2d = (double)b2[lane];

    for (unsigned int f = wave; f < nl; f += 4) {
        int ij = (int)lflags[f];
        int i = ij >> 10, j = ij & (N - 1);
        // u prefetch: lanes 0,1 each take one component (logs run in parallel
        // under exec mask later).
        double uvd = 0.0;
        if (lane < 2) uvd = (double)u[(((size_t)ij) << 1) + lane];
        {   // lane = k (two k's per lane), coalesced f64 loads
            int k0 = lane, k1 = lane + 64;
            double ai0 = A64[(size_t)i * H1 + k0], ai1 = A64[(size_t)i * H1 + k1];
            double aj0 = A64[(size_t)j * H1 + k0], aj1 = A64[(size_t)j * H1 + k1];
            double bi0 = B64[(size_t)i * H1 + k0], bi1 = B64[(size_t)i * H1 + k1];
            double bj0 = B64[(size_t)j * H1 + k0], bj1 = B64[(size_t)j * H1 + k1];
            double v;
            v = ai0 + bj0; h1s[wave][0][k0] = v > 0.0 ? v : 0.0;
            v = ai1 + bj1; h1s[wave][0][k1] = v > 0.0 ? v : 0.0;
            v = aj0 + bi0; h1s[wave][1][k0] = v > 0.0 ? v : 0.0;
            v = aj1 + bi1; h1s[wave][1][k1] = v > 0.0 ? v : 0.0;
        }
        // wave-local LDS fence: writes above complete before reads below
        asm volatile("s_waitcnt lgkmcnt(0)" ::: "memory");
        __builtin_amdgcn_wave_barrier();

        // 8 independent chains (we own repair numerics; any f64 order is
        // exact to ~1e-15): latency-hides the FMA dep chain.
        const double* __restrict__ hap = h1s[wave][0];
        const double* __restrict__ hbp = h1s[wave][1];
        double sa0 = 0.0, sa1 = 0.0, sa2 = 0.0, sa3 = 0.0;
        double sb0 = 0.0, sb1 = 0.0, sb2 = 0.0, sb3 = 0.0;
        #pragma unroll 2
        for (int k = 0; k < H1; k += 4) {
            double w0 = (double)W2[(k + 0) * H2 + lane];
            double w1 = (double)W2[(k + 1) * H2 + lane];
            double w2v = (double)W2[(k + 2) * H2 + lane];
            double w3v = (double)W2[(k + 3) * H2 + lane];
            sa0 += hap[k + 0] * w0;  sa1 += hap[k + 1] * w1;
            sa2 += hap[k + 2] * w2v; sa3 += hap[k + 3] * w3v;
            sb0 += hbp[k + 0] * w0;  sb1 += hbp[k + 1] * w1;
            sb2 += hbp[k + 2] * w2v; sb3 += hbp[k + 3] * w3v;
        }
        double sa = ((sa0 + sa1) + (sa2 + sa3)) + b2d;
        double sb = ((sb0 + sb1) + (sb2 + sb3)) + b2d;
        if (sa < 0.0) sa = 0.0;
        if (sb < 0.0) sb = 0.0;
        double da = sa * w3dd;
        double db = sb * w3dd;
        #pragma unroll
        for (int off = 32; off > 0; off >>= 1) {
            da += __shfl_down(da, off, 64);
            db += __shfl_down(db, off, 64);
        }
        // gumbel: lanes 0,1 execute the log routine once, in parallel
        double g = 0.0;
        if (lane < 2) g = -log(-log(uvd + 1e-10) + 1e-10);
        double g0 = __shfl(g, 0, 64);
        double g1 = __shfl(g, 1, 64);
        if (lane == 0) {
            double b3dd = (double)b3[1] - (double)b3[0];
            double Dv = 0.5 * (da + db) + b3dd + (g1 - g0);
            out[ij] = Dv > 0.0 ? 1.f : 0.f;
        }
        // DS in-order per wave: next iter's writes can't pass this iter's
        // reads; wave_barrier keeps the compiler from reordering.
        __builtin_amdgcn_wave_barrier();
    }
}

// ---------------------------------------------------------------------------
extern "C" void kernel_launch(void* const* d_in, const int* in_sizes, int n_in,
                              void* d_out, int out_size, void* d_ws, size_t ws_size,
                              hipStream_t stream) {
    const float* X  = (const float*)d_in[0];
    const float* W1 = (const float*)d_in[1];
    const float* b1 = (const float*)d_in[2];
    const float* W2 = (const float*)d_in[3];
    const float* b2 = (const float*)d_in[4];
    const float* W3 = (const float*)d_in[5];
    const float* b3 = (const float*)d_in[6];
    const float* u  = (const float*)d_in[7];
    float* out = (float*)d_out;

    // workspace layout (doubles first for alignment)
    double* A64 = (double*)d_ws;                         // 1 MB
    double* B64 = A64 + (size_t)N * H1;                  // 1 MB
    float* dmat = (float*)(B64 + (size_t)N * H1);        // 4 MB
    _Float16* A16 = (_Float16*)(dmat + (size_t)N * N);   // 256 KB
    _Float16* B16 = A16 + (size_t)N * H1;                // 256 KB

    precompute_kernel<<<N, 128, 0, stream>>>(X, W1, b1, A64, B64, A16, B16);
    pair_mlp_kernel<<<(N / 16) * (N / 64), 256, 0, stream>>>(A16, B16, W2, b2, W3, dmat);
    epilogue_repair_kernel<<<(N / 32) * (N / 32), 256, 0, stream>>>(
        dmat, A64, B64, W2, b2, W3, b3, u, out);
}